// Round 12
// baseline (933.943 us; speedup 1.0000x reference)
//
#include <hip/hip_runtime.h>
#include <math.h>

#define F_IN 256
#define HC   256   // H*C
#define H_   4
#define C_   64
#define KTOP 10
#define NEG_SLOPE 0.2f

// ================= GEMM: C[M,No] = A[M,K] @ B[No,K]^T (fp32) =================
// 128x128 tile, 8x8 per thread. Split column tile (cols tx*4 and 64+tx*4):
// Bs reads 2-way-aliased = free (R9-proven). Register diet: B fragments are
// loaded as two float4 halves consumed immediately (live b 8->4; staging quad
// not co-live with compute) -> target VGPR <=128 -> 4 blocks/CU -> the
// 782-block grid fits ONE residency round (R9-R11: 132 VGPR -> 3/CU -> 768+14
// two-round tail). NO forced bounds (R10: bounds(256,4) clamped to 64 VGPR ->
// spills, 544us). Bit-identical: each acc[i][j] accumulates exactly once per
// kk, kk ascending — intra-kk reorder doesn't change any per-element chain.
#define BM 128
#define BN 128
#define BK 16
#define LDP (BM + 4)   // padded LDS leading dim (keeps float4 alignment: 132%4==0)
__global__ __launch_bounds__(256) void gemm_nt(const float* __restrict__ A,
                                               const float* __restrict__ B,
                                               float* __restrict__ Cc,
                                               int M, int K, int No) {
  __shared__ float As[BK][LDP];
  __shared__ float Bs[BK][LDP];
  const int bm = blockIdx.x * BM;
  const int bn = blockIdx.y * BN;
  const int tid = threadIdx.x;
  const int tx = tid & 15, ty = tid >> 4;   // 16x16 compute grid
  const int lrow = tid >> 1;                // 0..127
  const int lk   = (tid & 1) << 3;          // 0 or 8
  const bool arow_ok = (bm + lrow < M);
  const float* aptr = A + (size_t)(bm + lrow) * K + lk;
  const float* bptr = B + (size_t)(bn + lrow) * K + lk;
  float acc[8][8] = {};
  for (int k0 = 0; k0 < K; k0 += BK) {
    float4 a0 = make_float4(0.f, 0.f, 0.f, 0.f), a1 = a0;
    if (arow_ok) {
      const float* ap = aptr + k0;
      a0 = *(const float4*)ap;
      a1 = *(const float4*)(ap + 4);
    }
    const float* bp = bptr + k0;
    float4 b0 = *(const float4*)bp;
    float4 b1 = *(const float4*)(bp + 4);
    __syncthreads();   // previous compute done; LDS free (loads already in flight)
    As[lk + 0][lrow] = a0.x; As[lk + 1][lrow] = a0.y; As[lk + 2][lrow] = a0.z; As[lk + 3][lrow] = a0.w;
    As[lk + 4][lrow] = a1.x; As[lk + 5][lrow] = a1.y; As[lk + 6][lrow] = a1.z; As[lk + 7][lrow] = a1.w;
    Bs[lk + 0][lrow] = b0.x; Bs[lk + 1][lrow] = b0.y; Bs[lk + 2][lrow] = b0.z; Bs[lk + 3][lrow] = b0.w;
    Bs[lk + 4][lrow] = b1.x; Bs[lk + 5][lrow] = b1.y; Bs[lk + 6][lrow] = b1.z; Bs[lk + 7][lrow] = b1.w;
    __syncthreads();
#pragma unroll
    for (int kk = 0; kk < BK; ++kk) {
      float a[8];
      *(float4*)&a[0] = *(const float4*)&As[kk][ty * 8];
      *(float4*)&a[4] = *(const float4*)&As[kk][ty * 8 + 4];
      {
        float4 bv = *(const float4*)&Bs[kk][tx * 4];          // 2-way, free
#pragma unroll
        for (int i = 0; i < 8; ++i) {
          acc[i][0] += a[i] * bv.x; acc[i][1] += a[i] * bv.y;
          acc[i][2] += a[i] * bv.z; acc[i][3] += a[i] * bv.w;
        }
      }
      {
        float4 bv = *(const float4*)&Bs[kk][64 + tx * 4];     // 2-way, free
#pragma unroll
        for (int i = 0; i < 8; ++i) {
          acc[i][4] += a[i] * bv.x; acc[i][5] += a[i] * bv.y;
          acc[i][6] += a[i] * bv.z; acc[i][7] += a[i] * bv.w;
        }
      }
    }
  }
#pragma unroll
  for (int i = 0; i < 8; ++i) {
    int r = bm + ty * 8 + i;
    if (r < M) {
      float* cp = Cc + (size_t)r * No + bn;
      *(float4*)(cp + tx * 4) = make_float4(acc[i][0], acc[i][1], acc[i][2], acc[i][3]);
      *(float4*)(cp + 64 + tx * 4) = make_float4(acc[i][4], acc[i][5], acc[i][6], acc[i][7]);
    }
  }
}

// ============ fused MLP head: out = relu(h2@Wl1^T+bl1)@Wl2^T+bl2 ============
// Post-top-K zone: re-association only perturbs the output continuously (~1e-6).
// 128 nodes/block (391 blocks -> single residency round). Padded LDS layouts:
// w1 stride 65, w2 stride 129 -> all reads/writes bank-conflict-free (R6's
// head_mlp had 3.6e7 conflicts from a stride-128 layout).
#define MLPB 128
__global__ __launch_bounds__(256) void mlp_fused(const float* __restrict__ h2,
                                                 const float* __restrict__ Wl1,
                                                 const float* __restrict__ bl1,
                                                 const float* __restrict__ Wl2,
                                                 const float* __restrict__ bl2,
                                                 float* __restrict__ out, int n_nodes) {
  __shared__ float w1[128][65];    // w1[r][c] = Wl1[r*64+c]
  __shared__ float w2[16][129];    // w2[o][k] = Wl2[o*128+k]
  __shared__ float xr[2][64];
  __shared__ float hid[2][128];
  int t = threadIdx.x;
  for (int i = t; i < 128 * 64; i += 256) w1[i >> 6][i & 63] = Wl1[i];
  for (int i = t; i < 16 * 128; i += 256) w2[i >> 7][i & 127] = Wl2[i];
  __syncthreads();
  int team = t >> 7;   // 0,1
  int tt = t & 127;
  int base = blockIdx.x * MLPB;
  for (int it = 0; it < MLPB; it += 2) {
    int n = base + it + team;
    bool ok = (n < n_nodes);
    if (ok && tt < 64) xr[team][tt] = h2[(size_t)n * C_ + tt];
    __syncthreads();
    if (ok) {
      float a = bl1[tt];
#pragma unroll 8
      for (int c = 0; c < 64; ++c) a += xr[team][c] * w1[tt][c];
      hid[team][tt] = fmaxf(a, 0.f);
    }
    __syncthreads();
    if (ok && tt < 16) {
      float o = bl2[tt];
#pragma unroll 16
      for (int k = 0; k < 128; ++k) o += hid[team][k] * w2[tt][k];
      out[(size_t)n * 16 + tt] = o;
    }
    __syncthreads();
  }
}

// ============ attention scores: a_s[n,h] = <xl[n,h,:], att_s[h,:]> ============
__global__ __launch_bounds__(256) void att_scores(const float* __restrict__ xl,
                                                  const float* __restrict__ att_s,
                                                  const float* __restrict__ att_d,
                                                  float* __restrict__ as_,
                                                  float* __restrict__ ad_, int n_nodes) {
  int n = blockIdx.x;               // one block per node, wave per head
  int h = threadIdx.x >> 6;
  int lane = threadIdx.x & 63;
  if (n >= n_nodes) return;
  float p = xl[(size_t)n * HC + h * C_ + lane];
  float s = p * att_s[h * C_ + lane];
  float d = p * att_d[h * C_ + lane];
#pragma unroll
  for (int off = 32; off >= 1; off >>= 1) {
    s += __shfl_down(s, off);
    d += __shfl_down(d, off);
  }
  if (lane == 0) {
    as_[n * H_ + h] = s;
    ad_[n * H_ + h] = d;
  }
}

// ====================== CSR build ======================
__global__ void count_edges(const int* __restrict__ dst, int E_, int* __restrict__ counts) {
  int e = blockIdx.x * blockDim.x + threadIdx.x;
  if (e < E_) atomicAdd(&counts[dst[e]], 1);
}

#define SCAN_T 1024
__global__ __launch_bounds__(SCAN_T) void scan_offsets(const int* __restrict__ counts,
                                                       int n_nodes, int* __restrict__ row_start,
                                                       int* __restrict__ wptr, int E_) {
  __shared__ int part[SCAN_T];
  int t = threadIdx.x;
  int chunk = (n_nodes + SCAN_T - 1) / SCAN_T;
  int lo = t * chunk;
  int hi = lo + chunk; if (hi > n_nodes) hi = n_nodes;
  int s = 0;
  for (int i = lo; i < hi; ++i) s += counts[i];
  part[t] = s;
  __syncthreads();
  for (int off = 1; off < SCAN_T; off <<= 1) {
    int v = (t >= off) ? part[t - off] : 0;
    __syncthreads();
    part[t] += v;
    __syncthreads();
  }
  int run = part[t] - s;   // exclusive prefix at chunk start
  for (int i = lo; i < hi; ++i) {
    int c = counts[i];
    row_start[i] = run;
    wptr[i] = run;
    run += c;
  }
  if (t == SCAN_T - 1) row_start[n_nodes] = E_;
}

__global__ void scatter_edges(const int* __restrict__ src, const int* __restrict__ dst, int E_,
                              int* __restrict__ wptr, int* __restrict__ csr_src) {
  int e = blockIdx.x * blockDim.x + threadIdx.x;
  if (e < E_) {
    int p = atomicAdd(&wptr[dst[e]], 1);
    csr_src[p] = src[e];
  }
}

// ====================== GAT aggregate (top-K softmax + gather) ======================
// Adaptive-width bitonic sort: W = smallest pow2 >= deg (deg is block-uniform).
// Same total-order comparator (v desc, orig-lane asc) over the same candidate
// multiset -> sorted prefix is bit-identical to the 64-wide sort (and to R1's
// iterative extraction). Tail (softmax + aggregation) verbatim R1.
template <int W>
__device__ inline void bitonic_desc(float& v, int& l, int lane) {
#pragma unroll
  for (int k = 2; k <= W; k <<= 1) {
#pragma unroll
    for (int j = k >> 1; j > 0; j >>= 1) {
      float ov = __shfl_xor(v, j);
      int   ol = __shfl_xor(l, j);
      int partner = lane ^ j;
      bool dirDesc = ((lane & k) == 0);
      bool mineFirst = (v > ov) || (v == ov && l < ol);
      bool keepMine = (dirDesc == (lane < partner)) ? mineFirst : !mineFirst;
      if (!keepMine) { v = ov; l = ol; }
    }
  }
}

template <int CONCAT>
__global__ __launch_bounds__(256) void gat_aggregate(const float* __restrict__ xl,
                                                     const float* __restrict__ as_,
                                                     const float* __restrict__ ad_,
                                                     const int* __restrict__ row_start,
                                                     const int* __restrict__ csr_src,
                                                     const float* __restrict__ bias,
                                                     float* __restrict__ out, int n_nodes) {
  __shared__ int   s_src[H_][16];
  __shared__ float s_w[H_][16];
  __shared__ float s_out[H_][C_];
  int n = blockIdx.x;
  int h = threadIdx.x >> 6;
  int lane = threadIdx.x & 63;
  int rs = row_start[n];
  int deg = row_start[n + 1] - rs;
  if (deg > 256) deg = 256;   // safety clamp (matches R1); max expected deg ~50
  float adv = ad_[n * H_ + h];
  int kcount = deg < KTOP ? deg : KTOP;

  if (deg <= 64) {
    // ---- fast path: one candidate per lane, adaptive-width bitonic sort desc ----
    float v; int sv;
    if (lane < deg) {
      int s = csr_src[rs + lane];
      float a = as_[s * H_ + h] + adv;
      v = (a >= 0.f) ? a : NEG_SLOPE * a;
      sv = s;
    } else {
      v = -INFINITY; sv = -1;
    }
    int l = lane;
    if (deg <= 16)      bitonic_desc<16>(v, l, lane);
    else if (deg <= 32) bitonic_desc<32>(v, l, lane);
    else                bitonic_desc<64>(v, l, lane);
    int swin = __shfl(sv, l);   // winner's src id (pull from original lane)
    if (lane < kcount) {
      s_src[h][lane] = swin;
      s_w[h][lane] = v;
    }
  } else {
    // ---- fallback: R1's original iterative extraction, verbatim ----
    float av[4]; int svr[4];
#pragma unroll
    for (int q = 0; q < 4; ++q) {
      int idx = lane + (q << 6);
      if (idx < deg) {
        int s = csr_src[rs + idx];
        float a = as_[s * H_ + h] + adv;
        av[q] = (a >= 0.f) ? a : NEG_SLOPE * a;
        svr[q] = s;
      } else {
        av[q] = -INFINITY; svr[q] = -1;
      }
    }
    for (int it = 0; it < kcount; ++it) {
      float best = av[0]; int bq = 0;
#pragma unroll
      for (int q = 1; q < 4; ++q)
        if (av[q] > best) { best = av[q]; bq = q; }
      float bv = best; int bl = lane;
#pragma unroll
      for (int off = 32; off >= 1; off >>= 1) {
        float ov = __shfl_down(bv, off);
        int   ol = __shfl_down(bl, off);
        if (ov > bv || (ov == bv && ol < bl)) { bv = ov; bl = ol; }
      }
      bl = __shfl(bl, 0);
      if (lane == bl) {
        s_src[h][it] = svr[bq];
        s_w[h][it] = best;
        av[bq] = -INFINITY;
      }
    }
  }
  __syncthreads();   // uniform: deg/kcount identical across the block's 4 waves

  // ---- softmax over kept edges (verbatim R1) ----
  float m = (kcount > 0) ? s_w[h][0] : 0.f;   // first entry = max
  float ex = (lane < kcount) ? expf(s_w[h][lane] - m) : 0.f;
  float denom = ex;
#pragma unroll
  for (int off = 32; off >= 1; off >>= 1) denom += __shfl_down(denom, off);
  denom = __shfl(denom, 0);
  float inv = (kcount > 0) ? 1.f / denom : 0.f;
  if (lane < kcount) s_w[h][lane] = ex * inv;
  __syncthreads();

  // ---- aggregate: lane = channel (verbatim R1) ----
  float acc = 0.f;
  for (int i = 0; i < kcount; ++i) {
    int s = s_src[h][i];
    float w = s_w[h][i];
    acc += w * xl[(size_t)s * HC + h * C_ + lane];
  }
  if (CONCAT) {
    out[(size_t)n * HC + h * C_ + lane] = acc + bias[h * C_ + lane];
  } else {
    s_out[h][lane] = acc;
    __syncthreads();
    if (h == 0) {
      float v2 = 0.25f * (s_out[0][lane] + s_out[1][lane] + s_out[2][lane] + s_out[3][lane]) +
                 bias[lane];
      out[(size_t)n * C_ + lane] = v2;
    }
  }
}

// ============================== launcher ==============================
extern "C" void kernel_launch(void* const* d_in, const int* in_sizes, int n_in,
                              void* d_out, int out_size, void* d_ws, size_t ws_size,
                              hipStream_t stream) {
  const float* x      = (const float*)d_in[0];
  const float* W1     = (const float*)d_in[1];
  const float* att_s1 = (const float*)d_in[2];
  const float* att_d1 = (const float*)d_in[3];
  const float* b1     = (const float*)d_in[4];
  const float* W2     = (const float*)d_in[5];
  const float* att_s2 = (const float*)d_in[6];
  const float* att_d2 = (const float*)d_in[7];
  const float* b2     = (const float*)d_in[8];
  const float* Wl1    = (const float*)d_in[9];
  const float* bl1    = (const float*)d_in[10];
  const float* Wl2    = (const float*)d_in[11];
  const float* bl2    = (const float*)d_in[12];
  const int*   eidx   = (const int*)d_in[13];

  const int N_ = in_sizes[0] / F_IN;     // 50000
  const int E_ = in_sizes[13] / 2;       // 800000
  const int* e_src = eidx;
  const int* e_dst = eidx + E_;

  // workspace layout (identical to R1/R6)
  char* base = (char*)d_ws;
  size_t off = 0;
  auto alloc = [&](size_t bytes) -> char* {
    char* p = base + off;
    off = (off + bytes + 255) & ~(size_t)255;
    return p;
  };
  float* xl      = (float*)alloc((size_t)N_ * HC * 4);
  float* hbuf    = (float*)alloc((size_t)N_ * HC * 4);   // h1; later h2 (N*64)
  float* as_     = (float*)alloc((size_t)N_ * H_ * 4);
  float* ad_     = (float*)alloc((size_t)N_ * H_ * 4);
  int* counts    = (int*)alloc((size_t)N_ * 4);
  int* row_start = (int*)alloc((size_t)(N_ + 1) * 4);
  int* wptr      = (int*)alloc((size_t)N_ * 4);
  int* csr_src   = (int*)alloc((size_t)E_ * 4);
  (void)ws_size;

  const int eb = (E_ + 255) / 256;

  // ---- CSR build (graph is shared by both conv layers) ----
  hipMemsetAsync(counts, 0, (size_t)N_ * 4, stream);
  count_edges<<<eb, 256, 0, stream>>>(e_dst, E_, counts);
  scan_offsets<<<1, SCAN_T, 0, stream>>>(counts, N_, row_start, wptr, E_);
  scatter_edges<<<eb, 256, 0, stream>>>(e_src, e_dst, E_, wptr, csr_src);

  dim3 ggrid((N_ + BM - 1) / BM, HC / BN);

  // ---- conv1 ----
  gemm_nt<<<ggrid, 256, 0, stream>>>(x, W1, xl, N_, F_IN, HC);
  att_scores<<<N_, 256, 0, stream>>>(xl, att_s1, att_d1, as_, ad_, N_);
  gat_aggregate<1><<<N_, 256, 0, stream>>>(xl, as_, ad_, row_start, csr_src, b1, hbuf, N_);

  // ---- conv2 ----
  gemm_nt<<<ggrid, 256, 0, stream>>>(hbuf, W2, xl, N_, HC, HC);
  att_scores<<<N_, 256, 0, stream>>>(xl, att_s2, att_d2, as_, ad_, N_);
  gat_aggregate<0><<<N_, 256, 0, stream>>>(xl, as_, ad_, row_start, csr_src, b2, hbuf, N_);

  // ---- fused MLP head ----
  mlp_fused<<<(N_ + MLPB - 1) / MLPB, 256, 0, stream>>>(hbuf, Wl1, bl1, Wl2, bl2,
                                                        (float*)d_out, N_);
}

// Round 13
// 855.599 us; speedup vs baseline: 1.0916x; 1.0916x over previous
//
#include <hip/hip_runtime.h>
#include <math.h>

#define F_IN 256
#define HC   256   // H*C
#define H_   4
#define C_   64
#define KTOP 10
#define NEG_SLOPE 0.2f

// ================= GEMM: C[M,No] = A[M,K] @ B[No,K]^T (fp32) =================
// 128x128 tile, 8x8 per thread. Split column tile (cols tx*4 and 64+tx*4):
// Bs reads 2-way-aliased = free (R9-proven). Register diet: B fragments are
// loaded as two float4 halves consumed immediately -> VGPR <=128 -> 4 blocks/CU
// -> 782-block grid in ONE residency round (R12 measured ~50us gain vs R11).
// NO forced bounds (R10: bounds(256,4) clamped to 64 VGPR -> spills, 544us).
// Bit-identical: each acc[i][j] accumulates once per kk, kk ascending.
#define BM 128
#define BN 128
#define BK 16
#define LDP (BM + 4)   // padded LDS leading dim (keeps float4 alignment: 132%4==0)
__global__ __launch_bounds__(256) void gemm_nt(const float* __restrict__ A,
                                               const float* __restrict__ B,
                                               float* __restrict__ Cc,
                                               int M, int K, int No) {
  __shared__ float As[BK][LDP];
  __shared__ float Bs[BK][LDP];
  const int bm = blockIdx.x * BM;
  const int bn = blockIdx.y * BN;
  const int tid = threadIdx.x;
  const int tx = tid & 15, ty = tid >> 4;   // 16x16 compute grid
  const int lrow = tid >> 1;                // 0..127
  const int lk   = (tid & 1) << 3;          // 0 or 8
  const bool arow_ok = (bm + lrow < M);
  const float* aptr = A + (size_t)(bm + lrow) * K + lk;
  const float* bptr = B + (size_t)(bn + lrow) * K + lk;
  float acc[8][8] = {};
  for (int k0 = 0; k0 < K; k0 += BK) {
    float4 a0 = make_float4(0.f, 0.f, 0.f, 0.f), a1 = a0;
    if (arow_ok) {
      const float* ap = aptr + k0;
      a0 = *(const float4*)ap;
      a1 = *(const float4*)(ap + 4);
    }
    const float* bp = bptr + k0;
    float4 b0 = *(const float4*)bp;
    float4 b1 = *(const float4*)(bp + 4);
    __syncthreads();   // previous compute done; LDS free (loads already in flight)
    As[lk + 0][lrow] = a0.x; As[lk + 1][lrow] = a0.y; As[lk + 2][lrow] = a0.z; As[lk + 3][lrow] = a0.w;
    As[lk + 4][lrow] = a1.x; As[lk + 5][lrow] = a1.y; As[lk + 6][lrow] = a1.z; As[lk + 7][lrow] = a1.w;
    Bs[lk + 0][lrow] = b0.x; Bs[lk + 1][lrow] = b0.y; Bs[lk + 2][lrow] = b0.z; Bs[lk + 3][lrow] = b0.w;
    Bs[lk + 4][lrow] = b1.x; Bs[lk + 5][lrow] = b1.y; Bs[lk + 6][lrow] = b1.z; Bs[lk + 7][lrow] = b1.w;
    __syncthreads();
#pragma unroll
    for (int kk = 0; kk < BK; ++kk) {
      float a[8];
      *(float4*)&a[0] = *(const float4*)&As[kk][ty * 8];
      *(float4*)&a[4] = *(const float4*)&As[kk][ty * 8 + 4];
      {
        float4 bv = *(const float4*)&Bs[kk][tx * 4];          // 2-way, free
#pragma unroll
        for (int i = 0; i < 8; ++i) {
          acc[i][0] += a[i] * bv.x; acc[i][1] += a[i] * bv.y;
          acc[i][2] += a[i] * bv.z; acc[i][3] += a[i] * bv.w;
        }
      }
      {
        float4 bv = *(const float4*)&Bs[kk][64 + tx * 4];     // 2-way, free
#pragma unroll
        for (int i = 0; i < 8; ++i) {
          acc[i][4] += a[i] * bv.x; acc[i][5] += a[i] * bv.y;
          acc[i][6] += a[i] * bv.z; acc[i][7] += a[i] * bv.w;
        }
      }
    }
  }
#pragma unroll
  for (int i = 0; i < 8; ++i) {
    int r = bm + ty * 8 + i;
    if (r < M) {
      float* cp = Cc + (size_t)r * No + bn;
      *(float4*)(cp + tx * 4) = make_float4(acc[i][0], acc[i][1], acc[i][2], acc[i][3]);
      *(float4*)(cp + 64 + tx * 4) = make_float4(acc[i][4], acc[i][5], acc[i][6], acc[i][7]);
    }
  }
}

// ============ MLP layer 1: hid = relu(A @ B^T + bias), same tiling ============
// R11-proven split head (R12's fused mlp regressed to 168us: 192 barriers/block,
// phase-idle threads). Post-top-K zone: re-association harmless.
__global__ __launch_bounds__(256) void gemm_bias_relu(const float* __restrict__ A,
                                                      const float* __restrict__ B,
                                                      const float* __restrict__ bias,
                                                      float* __restrict__ Cc,
                                                      int M, int K, int No) {
  __shared__ float As[BK][LDP];
  __shared__ float Bs[BK][LDP];
  const int bm = blockIdx.x * BM;
  const int bn = blockIdx.y * BN;
  const int tid = threadIdx.x;
  const int tx = tid & 15, ty = tid >> 4;
  const int lrow = tid >> 1;
  const int lk   = (tid & 1) << 3;
  const bool arow_ok = (bm + lrow < M);
  const bool brow_ok = (bn + lrow < No);
  const float* aptr = A + (size_t)(bm + lrow) * K + lk;
  const float* bptr = B + (size_t)(bn + lrow) * K + lk;
  float acc[8][8] = {};
  for (int k0 = 0; k0 < K; k0 += BK) {
    float4 a0 = make_float4(0.f, 0.f, 0.f, 0.f), a1 = a0, b0 = a0, b1 = a0;
    if (arow_ok) {
      const float* ap = aptr + k0;
      a0 = *(const float4*)ap;
      a1 = *(const float4*)(ap + 4);
    }
    if (brow_ok) {
      const float* bp = bptr + k0;
      b0 = *(const float4*)bp;
      b1 = *(const float4*)(bp + 4);
    }
    __syncthreads();
    As[lk + 0][lrow] = a0.x; As[lk + 1][lrow] = a0.y; As[lk + 2][lrow] = a0.z; As[lk + 3][lrow] = a0.w;
    As[lk + 4][lrow] = a1.x; As[lk + 5][lrow] = a1.y; As[lk + 6][lrow] = a1.z; As[lk + 7][lrow] = a1.w;
    Bs[lk + 0][lrow] = b0.x; Bs[lk + 1][lrow] = b0.y; Bs[lk + 2][lrow] = b0.z; Bs[lk + 3][lrow] = b0.w;
    Bs[lk + 4][lrow] = b1.x; Bs[lk + 5][lrow] = b1.y; Bs[lk + 6][lrow] = b1.z; Bs[lk + 7][lrow] = b1.w;
    __syncthreads();
#pragma unroll
    for (int kk = 0; kk < BK; ++kk) {
      float a[8];
      *(float4*)&a[0] = *(const float4*)&As[kk][ty * 8];
      *(float4*)&a[4] = *(const float4*)&As[kk][ty * 8 + 4];
      {
        float4 bv = *(const float4*)&Bs[kk][tx * 4];
#pragma unroll
        for (int i = 0; i < 8; ++i) {
          acc[i][0] += a[i] * bv.x; acc[i][1] += a[i] * bv.y;
          acc[i][2] += a[i] * bv.z; acc[i][3] += a[i] * bv.w;
        }
      }
      {
        float4 bv = *(const float4*)&Bs[kk][64 + tx * 4];
#pragma unroll
        for (int i = 0; i < 8; ++i) {
          acc[i][4] += a[i] * bv.x; acc[i][5] += a[i] * bv.y;
          acc[i][6] += a[i] * bv.z; acc[i][7] += a[i] * bv.w;
        }
      }
    }
  }
#pragma unroll
  for (int i = 0; i < 8; ++i) {
    int r = bm + ty * 8 + i;
    if (r < M) {
      float* cp = Cc + (size_t)r * No + bn;
#pragma unroll
      for (int j = 0; j < 4; ++j) {
        int col = tx * 4 + j;
        cp[col] = fmaxf(acc[i][j] + bias[bn + col], 0.f);
      }
#pragma unroll
      for (int j = 0; j < 4; ++j) {
        int col = 64 + tx * 4 + j;
        cp[col] = fmaxf(acc[i][4 + j] + bias[bn + col], 0.f);
      }
    }
  }
}

// ============ MLP layer 2: out[n,o] = <hid[n,:], Wl2[o,:]> + bl2[o] ============
__global__ __launch_bounds__(256) void head_out(const float* __restrict__ hid,
                                                const float* __restrict__ Wl2,
                                                const float* __restrict__ bl2,
                                                float* __restrict__ out, int n_nodes) {
  int t = blockIdx.x * 256 + threadIdx.x;
  int n = t >> 4, o = t & 15;
  if (n >= n_nodes) return;
  const float4* hp = (const float4*)(hid + (size_t)n * 128);
  const float4* wp = (const float4*)(Wl2 + (size_t)o * 128);
  float acc = bl2[o];
#pragma unroll
  for (int k = 0; k < 32; ++k) {
    float4 hv = hp[k], wv = wp[k];
    acc += hv.x * wv.x + hv.y * wv.y + hv.z * wv.z + hv.w * wv.w;
  }
  out[(size_t)n * 16 + o] = acc;
}

// ============ attention scores: a_s[n,h] = <xl[n,h,:], att_s[h,:]> ============
__global__ __launch_bounds__(256) void att_scores(const float* __restrict__ xl,
                                                  const float* __restrict__ att_s,
                                                  const float* __restrict__ att_d,
                                                  float* __restrict__ as_,
                                                  float* __restrict__ ad_, int n_nodes) {
  int n = blockIdx.x;               // one block per node, wave per head
  int h = threadIdx.x >> 6;
  int lane = threadIdx.x & 63;
  if (n >= n_nodes) return;
  float p = xl[(size_t)n * HC + h * C_ + lane];
  float s = p * att_s[h * C_ + lane];
  float d = p * att_d[h * C_ + lane];
#pragma unroll
  for (int off = 32; off >= 1; off >>= 1) {
    s += __shfl_down(s, off);
    d += __shfl_down(d, off);
  }
  if (lane == 0) {
    as_[n * H_ + h] = s;
    ad_[n * H_ + h] = d;
  }
}

// ====================== CSR build ======================
__global__ void count_edges(const int* __restrict__ dst, int E_, int* __restrict__ counts) {
  int e = blockIdx.x * blockDim.x + threadIdx.x;
  if (e < E_) atomicAdd(&counts[dst[e]], 1);
}

#define SCAN_T 1024
__global__ __launch_bounds__(SCAN_T) void scan_offsets(const int* __restrict__ counts,
                                                       int n_nodes, int* __restrict__ row_start,
                                                       int* __restrict__ wptr, int E_) {
  __shared__ int part[SCAN_T];
  int t = threadIdx.x;
  int chunk = (n_nodes + SCAN_T - 1) / SCAN_T;
  int lo = t * chunk;
  int hi = lo + chunk; if (hi > n_nodes) hi = n_nodes;
  int s = 0;
  for (int i = lo; i < hi; ++i) s += counts[i];
  part[t] = s;
  __syncthreads();
  for (int off = 1; off < SCAN_T; off <<= 1) {
    int v = (t >= off) ? part[t - off] : 0;
    __syncthreads();
    part[t] += v;
    __syncthreads();
  }
  int run = part[t] - s;   // exclusive prefix at chunk start
  for (int i = lo; i < hi; ++i) {
    int c = counts[i];
    row_start[i] = run;
    wptr[i] = run;
    run += c;
  }
  if (t == SCAN_T - 1) row_start[n_nodes] = E_;
}

__global__ void scatter_edges(const int* __restrict__ src, const int* __restrict__ dst, int E_,
                              int* __restrict__ wptr, int* __restrict__ csr_src) {
  int e = blockIdx.x * blockDim.x + threadIdx.x;
  if (e < E_) {
    int p = atomicAdd(&wptr[dst[e]], 1);
    csr_src[p] = src[e];
  }
}

// ====================== GAT aggregate (top-K softmax + gather) ======================
// Adaptive-width bitonic sort: W = smallest pow2 >= deg (deg is block-uniform).
// Same total-order comparator (v desc, orig-lane asc) over the same candidate
// multiset -> sorted prefix is bit-identical to the 64-wide sort (and to R1's
// iterative extraction). Tail (softmax + aggregation) verbatim R1.
template <int W>
__device__ inline void bitonic_desc(float& v, int& l, int lane) {
#pragma unroll
  for (int k = 2; k <= W; k <<= 1) {
#pragma unroll
    for (int j = k >> 1; j > 0; j >>= 1) {
      float ov = __shfl_xor(v, j);
      int   ol = __shfl_xor(l, j);
      int partner = lane ^ j;
      bool dirDesc = ((lane & k) == 0);
      bool mineFirst = (v > ov) || (v == ov && l < ol);
      bool keepMine = (dirDesc == (lane < partner)) ? mineFirst : !mineFirst;
      if (!keepMine) { v = ov; l = ol; }
    }
  }
}

template <int CONCAT>
__global__ __launch_bounds__(256) void gat_aggregate(const float* __restrict__ xl,
                                                     const float* __restrict__ as_,
                                                     const float* __restrict__ ad_,
                                                     const int* __restrict__ row_start,
                                                     const int* __restrict__ csr_src,
                                                     const float* __restrict__ bias,
                                                     float* __restrict__ out, int n_nodes) {
  __shared__ int   s_src[H_][16];
  __shared__ float s_w[H_][16];
  __shared__ float s_out[H_][C_];
  int n = blockIdx.x;
  int h = threadIdx.x >> 6;
  int lane = threadIdx.x & 63;
  int rs = row_start[n];
  int deg = row_start[n + 1] - rs;
  if (deg > 256) deg = 256;   // safety clamp (matches R1); max expected deg ~50
  float adv = ad_[n * H_ + h];
  int kcount = deg < KTOP ? deg : KTOP;

  if (deg <= 64) {
    // ---- fast path: one candidate per lane, adaptive-width bitonic sort desc ----
    float v; int sv;
    if (lane < deg) {
      int s = csr_src[rs + lane];
      float a = as_[s * H_ + h] + adv;
      v = (a >= 0.f) ? a : NEG_SLOPE * a;
      sv = s;
    } else {
      v = -INFINITY; sv = -1;
    }
    int l = lane;
    if (deg <= 16)      bitonic_desc<16>(v, l, lane);
    else if (deg <= 32) bitonic_desc<32>(v, l, lane);
    else                bitonic_desc<64>(v, l, lane);
    int swin = __shfl(sv, l);   // winner's src id (pull from original lane)
    if (lane < kcount) {
      s_src[h][lane] = swin;
      s_w[h][lane] = v;
    }
  } else {
    // ---- fallback: R1's original iterative extraction, verbatim ----
    float av[4]; int svr[4];
#pragma unroll
    for (int q = 0; q < 4; ++q) {
      int idx = lane + (q << 6);
      if (idx < deg) {
        int s = csr_src[rs + idx];
        float a = as_[s * H_ + h] + adv;
        av[q] = (a >= 0.f) ? a : NEG_SLOPE * a;
        svr[q] = s;
      } else {
        av[q] = -INFINITY; svr[q] = -1;
      }
    }
    for (int it = 0; it < kcount; ++it) {
      float best = av[0]; int bq = 0;
#pragma unroll
      for (int q = 1; q < 4; ++q)
        if (av[q] > best) { best = av[q]; bq = q; }
      float bv = best; int bl = lane;
#pragma unroll
      for (int off = 32; off >= 1; off >>= 1) {
        float ov = __shfl_down(bv, off);
        int   ol = __shfl_down(bl, off);
        if (ov > bv || (ov == bv && ol < bl)) { bv = ov; bl = ol; }
      }
      bl = __shfl(bl, 0);
      if (lane == bl) {
        s_src[h][it] = svr[bq];
        s_w[h][it] = best;
        av[bq] = -INFINITY;
      }
    }
  }
  __syncthreads();   // uniform: deg/kcount identical across the block's 4 waves

  // ---- softmax over kept edges (verbatim R1) ----
  float m = (kcount > 0) ? s_w[h][0] : 0.f;   // first entry = max
  float ex = (lane < kcount) ? expf(s_w[h][lane] - m) : 0.f;
  float denom = ex;
#pragma unroll
  for (int off = 32; off >= 1; off >>= 1) denom += __shfl_down(denom, off);
  denom = __shfl(denom, 0);
  float inv = (kcount > 0) ? 1.f / denom : 0.f;
  if (lane < kcount) s_w[h][lane] = ex * inv;
  __syncthreads();

  // ---- aggregate: lane = channel (verbatim R1) ----
  float acc = 0.f;
  for (int i = 0; i < kcount; ++i) {
    int s = s_src[h][i];
    float w = s_w[h][i];
    acc += w * xl[(size_t)s * HC + h * C_ + lane];
  }
  if (CONCAT) {
    out[(size_t)n * HC + h * C_ + lane] = acc + bias[h * C_ + lane];
  } else {
    s_out[h][lane] = acc;
    __syncthreads();
    if (h == 0) {
      float v2 = 0.25f * (s_out[0][lane] + s_out[1][lane] + s_out[2][lane] + s_out[3][lane]) +
                 bias[lane];
      out[(size_t)n * C_ + lane] = v2;
    }
  }
}

// ============================== launcher ==============================
extern "C" void kernel_launch(void* const* d_in, const int* in_sizes, int n_in,
                              void* d_out, int out_size, void* d_ws, size_t ws_size,
                              hipStream_t stream) {
  const float* x      = (const float*)d_in[0];
  const float* W1     = (const float*)d_in[1];
  const float* att_s1 = (const float*)d_in[2];
  const float* att_d1 = (const float*)d_in[3];
  const float* b1     = (const float*)d_in[4];
  const float* W2     = (const float*)d_in[5];
  const float* att_s2 = (const float*)d_in[6];
  const float* att_d2 = (const float*)d_in[7];
  const float* b2     = (const float*)d_in[8];
  const float* Wl1    = (const float*)d_in[9];
  const float* bl1    = (const float*)d_in[10];
  const float* Wl2    = (const float*)d_in[11];
  const float* bl2    = (const float*)d_in[12];
  const int*   eidx   = (const int*)d_in[13];

  const int N_ = in_sizes[0] / F_IN;     // 50000
  const int E_ = in_sizes[13] / 2;       // 800000
  const int* e_src = eidx;
  const int* e_dst = eidx + E_;

  // workspace layout (identical to R1/R6)
  char* base = (char*)d_ws;
  size_t off = 0;
  auto alloc = [&](size_t bytes) -> char* {
    char* p = base + off;
    off = (off + bytes + 255) & ~(size_t)255;
    return p;
  };
  float* xl      = (float*)alloc((size_t)N_ * HC * 4);
  float* hbuf    = (float*)alloc((size_t)N_ * HC * 4);   // h1; later h2 (N*64)
  float* as_     = (float*)alloc((size_t)N_ * H_ * 4);
  float* ad_     = (float*)alloc((size_t)N_ * H_ * 4);
  int* counts    = (int*)alloc((size_t)N_ * 4);
  int* row_start = (int*)alloc((size_t)(N_ + 1) * 4);
  int* wptr      = (int*)alloc((size_t)N_ * 4);
  int* csr_src   = (int*)alloc((size_t)E_ * 4);
  (void)ws_size;
  // hid buffer for MLP layer 1 reuses xl's space (xl is dead after gat_aggregate<0>)
  float* hidbuf  = xl;   // N*128 floats <= N*256 slot

  const int eb = (E_ + 255) / 256;

  // ---- CSR build (graph is shared by both conv layers) ----
  hipMemsetAsync(counts, 0, (size_t)N_ * 4, stream);
  count_edges<<<eb, 256, 0, stream>>>(e_dst, E_, counts);
  scan_offsets<<<1, SCAN_T, 0, stream>>>(counts, N_, row_start, wptr, E_);
  scatter_edges<<<eb, 256, 0, stream>>>(e_src, e_dst, E_, wptr, csr_src);

  dim3 ggrid((N_ + BM - 1) / BM, HC / BN);

  // ---- conv1 ----
  gemm_nt<<<ggrid, 256, 0, stream>>>(x, W1, xl, N_, F_IN, HC);
  att_scores<<<N_, 256, 0, stream>>>(xl, att_s1, att_d1, as_, ad_, N_);
  gat_aggregate<1><<<N_, 256, 0, stream>>>(xl, as_, ad_, row_start, csr_src, b1, hbuf, N_);

  // ---- conv2 ----
  gemm_nt<<<ggrid, 256, 0, stream>>>(hbuf, W2, xl, N_, HC, HC);
  att_scores<<<N_, 256, 0, stream>>>(xl, att_s2, att_d2, as_, ad_, N_);
  gat_aggregate<0><<<N_, 256, 0, stream>>>(xl, as_, ad_, row_start, csr_src, b2, hbuf, N_);

  // ---- MLP head: hid = relu(h2 @ Wl1^T + bl1); out = hid @ Wl2^T + bl2 ----
  dim3 hgrid((N_ + BM - 1) / BM, 1);
  gemm_bias_relu<<<hgrid, 256, 0, stream>>>(hbuf, Wl1, bl1, hidbuf, N_, C_, 128);
  head_out<<<(N_ * 16 + 255) / 256, 256, 0, stream>>>(hidbuf, Wl2, bl2, (float*)d_out, N_);
}